// Round 1
// baseline (506.770 us; speedup 1.0000x reference)
//
#include <hip/hip_runtime.h>
#include <math.h>

// DILATE-style loss: 0.5*mean(softDTW) + 0.5*sum(E*Omega)/(B*N*N) + MSE
// B=64, N=256, K=1, gamma=0.01, INF=1e8.
//
// ws layout: [0, 16MB)  : R matrices, row-major interior, per-batch stride N*N floats
//            [16MB, +24): 3 double accumulators {sdtw_sum, temporal_sum, mse_sum}

#define BB 64
#define NN 256
#define GAMMA_F 0.01f
#define INVG 100.0f
#define INF_F 100000000.0f
#define RSTRIDE ((size_t)NN * NN)

__global__ __launch_bounds__(64) void init_acc_kernel(double* acc) {
  if (threadIdx.x < 3) acc[threadIdx.x] = 0.0;
}

__global__ __launch_bounds__(256) void sdtw_kernel(
    const float* __restrict__ input, const float* __restrict__ target,
    float* __restrict__ Rg, double* __restrict__ acc) {
  const int b = blockIdx.x;
  const int tid = threadIdx.x;
  const int i = tid + 1;  // DTW row 1..N (target index i-1)

  __shared__ float xs[NN];             // input[b,:,0]
  __shared__ float ts[NN];             // target[b,:,0]
  __shared__ float ring[3][NN + 1];    // R anti-diagonal ring (fwd & bwd)
  __shared__ float ering[3][NN + 1];   // E anti-diagonal ring (bwd)
  __shared__ double red[256];

  const float* __restrict__ xb = input + b * NN;
  const float* __restrict__ tb = target + b * NN;
  float* __restrict__ Rb = Rg + (size_t)b * RSTRIDE;

  const float xv = xb[tid];
  const float tv = tb[tid];
  xs[tid] = xv;
  ts[tid] = tv;
  const float ti = tv;  // t[i-1], constant for this thread
  const float dmse = xv - tv;
  const float mse_loc = dmse * dmse;

  // ---- forward init: diag0 = {R[0][0]=0, rest INF}; diag1 = all INF ----
  ring[0][tid] = (tid == 0) ? 0.0f : INF_F;
  ring[1][tid] = INF_F;
  if (tid == 0) { ring[0][NN] = INF_F; ring[1][NN] = INF_F; }
  __syncthreads();

  // ---- forward scan over anti-diagonals d = 2..2N ----
  int r0 = 0, r1 = 1, r2 = 2;  // r0: diag d-2, r1: diag d-1, r2: new diag d
  for (int d = 2; d <= 2 * NN; ++d) {
    const int j = d - i;
    float rn = INF_F;
    if (j >= 1 && j <= NN) {
      const float a  = ring[r0][i - 1];  // R[i-1][j-1]
      const float bv = ring[r1][i - 1];  // R[i-1][j]
      const float c  = ring[r1][i];      // R[i][j-1]
      const float m  = fminf(a, fminf(bv, c));
      const float s  = expf((m - a) * INVG) + expf((m - bv) * INVG) + expf((m - c) * INVG);
      const float smin = m - GAMMA_F * logf(s);  // == -g*logsumexp(-v/g)
      const float dx = ti - xs[j - 1];           // D[i][j] = (t[i-1]-x[j-1])^2
      rn = fmaf(dx, dx, smin);
      Rb[(size_t)tid * NN + (j - 1)] = rn;       // own-row streaming store
    }
    ring[r2][i] = rn;
    if (tid == 0) ring[r2][0] = INF_F;  // row 0 boundary of every diagonal
    __syncthreads();
    const int t = r0; r0 = r1; r1 = r2; r2 = t;
  }

  // R[N][N] is in ring[r1][NN]
  if (tid == 0) atomicAdd(&acc[0], (double)ring[r1][NN]);

  // ---- backward: E[i][j] = sum over successors of exp((R_s - D_s - R_ij)/g)*E_s ----
  // R ring reuse: rb1 currently holds diag 2N (from forward), rb2 content never read
  // (wc guard excludes diag 2N+1), rb0 is loaded fresh each iteration.
  int rb0 = r0, rb1 = r1, rb2 = r2;
  int e0 = 0, e1 = 1, e2 = 2;  // e1: diag d+1, e2: diag d+2, e0: new diag d
  ering[0][tid] = 0.0f; ering[1][tid] = 0.0f; ering[2][tid] = 0.0f;
  if (tid == 0) {
    ering[0][NN] = 0.0f; ering[2][NN] = 0.0f;
    ering[1][NN] = 1.0f;  // E[N][N] = 1 seeds diag 2N
  }
  double tsum = 0.0;
  __syncthreads();

  for (int d = 2 * NN - 1; d >= 2; --d) {
    const int j = d - i;
    float En = 0.0f;
    if (j >= 1 && j <= NN) {
      const float Rij = Rb[(size_t)tid * NN + (j - 1)];  // own-row streaming load
      float w = 0.0f;
      if (i < NN) {  // successor (i+1, j) on diag d+1
        const float Ra  = ring[rb1][i + 1];
        const float dta = ts[i] - xs[j - 1];   // D[i+1][j]
        w += expf((Ra - dta * dta - Rij) * INVG) * ering[e1][i + 1];
      }
      if (j < NN) {  // successor (i, j+1) on diag d+1
        const float Rv  = ring[rb1][i];
        const float dtb = ti - xs[j];          // D[i][j+1]
        w += expf((Rv - dtb * dtb - Rij) * INVG) * ering[e1][i];
      }
      if (i < NN && j < NN) {  // successor (i+1, j+1) on diag d+2
        const float Rc  = ring[rb2][i + 1];
        const float dtc = ts[i] - xs[j];       // D[i+1][j+1]
        w += expf((Rc - dtc * dtc - Rij) * INVG) * ering[e2][i + 1];
      }
      En = w;
      const float dij = (float)(i - j);
      tsum += (double)(En * dij * dij);
      ring[rb0][i] = Rij;  // current diag becomes rb1 next iteration
    }
    ering[e0][i] = En;
    __syncthreads();
    int t = rb2; rb2 = rb1; rb1 = rb0; rb0 = t;
    t = e2; e2 = e1; e1 = e0; e0 = t;
  }

  // ---- block reductions ----
  red[tid] = tsum;
  __syncthreads();
  for (int s2 = 128; s2 > 0; s2 >>= 1) {
    if (tid < s2) red[tid] += red[tid + s2];
    __syncthreads();
  }
  if (tid == 0) atomicAdd(&acc[1], red[0]);
  __syncthreads();

  red[tid] = (double)mse_loc;
  __syncthreads();
  for (int s2 = 128; s2 > 0; s2 >>= 1) {
    if (tid < s2) red[tid] += red[tid + s2];
    __syncthreads();
  }
  if (tid == 0) atomicAdd(&acc[2], red[0]);
}

__global__ void finalize_kernel(const double* __restrict__ acc, float* __restrict__ out) {
  if (threadIdx.x == 0 && blockIdx.x == 0) {
    const double loss_shape    = acc[0] / (double)BB;
    const double loss_temporal = acc[1] / ((double)BB * NN * NN);
    const double mse           = acc[2] / ((double)BB * NN);  // B*N*K elements
    out[0] = (float)(0.5 * loss_shape + 0.5 * loss_temporal + mse);
  }
}

extern "C" void kernel_launch(void* const* d_in, const int* in_sizes, int n_in,
                              void* d_out, int out_size, void* d_ws, size_t ws_size,
                              hipStream_t stream) {
  const float* input  = (const float*)d_in[0];
  const float* target = (const float*)d_in[1];
  float* Rg   = (float*)d_ws;
  double* acc = (double*)((char*)d_ws + (size_t)BB * RSTRIDE * sizeof(float));
  float* out  = (float*)d_out;

  init_acc_kernel<<<1, 64, 0, stream>>>(acc);
  sdtw_kernel<<<BB, 256, 0, stream>>>(input, target, Rg, acc);
  finalize_kernel<<<1, 64, 0, stream>>>(acc, out);
}

// Round 2
// 343.094 us; speedup vs baseline: 1.4771x; 1.4771x over previous
//
#include <hip/hip_runtime.h>
#include <math.h>

// DILATE loss: 0.5*mean(softDTW) + 0.5*sum(E*Omega)/(B*N*N) + MSE
// B=64, N=256, K=1, gamma=0.01.
// One wave (64 lanes) per batch; lane p owns rows 4p+1..4p+4. Pipelined
// anti-diagonal skew: lane p does column j=s-p+1 at step s (forward),
// j=N-u+(63-p) at step u (backward). Boundary values travel via shuffles —
// zero barriers in the scan. R stored in staircase slabs R[s][lane] (float4,
// coalesced); backward reads slab 318-u with 1-iteration prefetch.
//
// ws: [0, 64*319*64*16 B) R slabs; then 64*3 doubles {sdtw, tsum, mse} per batch.

#define BB 64
#define NN 256
#define PP 64
#define NSLAB (NN + PP - 1)  // 319
#define INF_F 100000000.0f
#define ESC 144.26950408889634f   /* (1/gamma) * log2(e) */
#define LSC 0.006931471805599453f /* gamma * ln(2) */

__device__ __forceinline__ float fwd_cell(float a, float b, float c, float ti, float xj) {
  const float m = fminf(a, fminf(b, c));
  const float s = exp2f((m - a) * ESC) + exp2f((m - b) * ESC) + exp2f((m - c) * ESC);
  const float smin = m - LSC * log2f(s);
  const float dx = ti - xj;
  return fmaf(dx, dx, smin);
}

__global__ __launch_bounds__(64) void sdtw_kernel(
    const float* __restrict__ input, const float* __restrict__ target,
    float4* __restrict__ Rws, double* __restrict__ partial) {
  const int b = blockIdx.x;
  const int p = threadIdx.x;
  __shared__ float xs[NN + 1];

  const float4 xv4 = ((const float4*)(input + b * NN))[p];
  const float4 tv4 = ((const float4*)(target + b * NN))[p];
  ((float4*)xs)[p] = xv4;
  if (p == 0) xs[NN] = 0.0f;  // guard for speculative xs[j] read at j==NN
  const float t0 = tv4.x, t1 = tv4.y, t2 = tv4.z, t3 = tv4.w;
  const float t4 = __shfl_down(t0, 1);  // t of lane p+1's top row (guarded for p=63)
  __syncthreads();

  double msel = 0.0;
  {
    const float d0 = xv4.x - tv4.x, d1 = xv4.y - tv4.y;
    const float d2 = xv4.z - tv4.z, d3 = xv4.w - tv4.w;
    msel = (double)(d0 * d0) + (double)(d1 * d1) + (double)(d2 * d2) + (double)(d3 * d3);
  }

  float4* __restrict__ Rb = Rws + (size_t)b * NSLAB * PP;

  // ---------------- forward ----------------
  float prev0 = INF_F, prev1 = INF_F, prev2 = INF_F, prev3 = INF_F;
  float cur0 = INF_F, cur1 = INF_F, cur2 = INF_F, cur3 = INF_F;
  float tl = (p == 0) ? 0.0f : INF_F;  // R[top-1][j-1]
  float ttop = INF_F;                  // R[top-1][j]
  for (int s = 0; s < NSLAB; ++s) {
    const int j = s - p + 1;
    const bool act = (j >= 1) & (j <= NN);
    if (act) {
      const float xj = xs[j - 1];
      cur0 = fwd_cell(tl, ttop, prev0, t0, xj);
      cur1 = fwd_cell(prev0, cur0, prev1, t1, xj);
      cur2 = fwd_cell(prev1, cur1, prev2, t2, xj);
      cur3 = fwd_cell(prev2, cur2, prev3, t3, xj);
      Rb[(size_t)s * PP + p] = make_float4(cur0, cur1, cur2, cur3);
      prev0 = cur0; prev1 = cur1; prev2 = cur2; prev3 = cur3;
    }
    const float bot = act ? cur3 : INF_F;
    const float nt = __shfl_up(bot, 1);  // lane p-1's bottom row, column j+1 (for next step)
    tl = ttop;
    ttop = (p == 0) ? INF_F : nt;  // row 0 is INF for all j>=1
  }
  const float r_nn = __shfl(cur3, PP - 1);  // R[N][N]

  // ---------------- backward ----------------
  // E[i][j] = sum over successors s of exp((R_s - D_s - R_ij)/g) * E_s; E[N][N]=1.
  float Rr0 = 0.f, Rr1 = 0.f, Rr2 = 0.f, Rr3 = 0.f;  // R[i_k][j+1]
  float Er0 = 0.f, Er1 = 0.f, Er2 = 0.f, Er3 = 0.f;  // E[i_k][j+1]
  float bR0 = 0.f, bR1 = 0.f, bE0 = 0.f, bE1 = 0.f;  // below-top at col j, j+1
  double tsum = 0.0;

  float4 Rc = Rb[(size_t)(NSLAB - 1) * PP + p];  // prefetch slab for u=0
  for (int u = 0; u < NSLAB; ++u) {
    const int j = NN - u + (PP - 1 - p);
    const bool act = (j >= 1) & (j <= NN);
    const int sn = (NSLAB - 2 - u) < 0 ? 0 : (NSLAB - 2 - u);
    const float4 Rnext = Rb[(size_t)sn * PP + p];  // prefetch next slab (harmless re-read at end)
    float e0 = 0.f, e1 = 0.f, e2 = 0.f, e3 = 0.f;
    if (act) {
      const float xj = xs[j - 1];
      const float xjp = xs[j];
      const bool jr = (j < NN);
      const bool pb = (p < PP - 1);
      // k=3 (bottom row of strip): successors from lane p+1 via shuffled bR/bE
      {
        float w;
        const float da = t4 - xj;
        w = pb ? exp2f((bR0 - da * da - Rc.w) * ESC) * bE0 : 0.0f;
        const float dr = t3 - xjp;
        w += jr ? exp2f((Rr3 - dr * dr - Rc.w) * ESC) * Er3 : 0.0f;
        const float dd = t4 - xjp;
        w += (pb & jr) ? exp2f((bR1 - dd * dd - Rc.w) * ESC) * bE1 : 0.0f;
        e3 = w;
      }
      if ((p == PP - 1) & (j == NN)) e3 = 1.0f;  // seed E[N][N]
      // k=2
      {
        const float da = t3 - xj;
        float w = exp2f((Rc.w - da * da - Rc.z) * ESC) * e3;
        const float dr = t2 - xjp;
        w += jr ? exp2f((Rr2 - dr * dr - Rc.z) * ESC) * Er2 : 0.0f;
        const float dd = t3 - xjp;
        w += jr ? exp2f((Rr3 - dd * dd - Rc.z) * ESC) * Er3 : 0.0f;
        e2 = w;
      }
      // k=1
      {
        const float da = t2 - xj;
        float w = exp2f((Rc.z - da * da - Rc.y) * ESC) * e2;
        const float dr = t1 - xjp;
        w += jr ? exp2f((Rr1 - dr * dr - Rc.y) * ESC) * Er1 : 0.0f;
        const float dd = t2 - xjp;
        w += jr ? exp2f((Rr2 - dd * dd - Rc.y) * ESC) * Er2 : 0.0f;
        e1 = w;
      }
      // k=0 (top row of strip)
      {
        const float da = t1 - xj;
        float w = exp2f((Rc.y - da * da - Rc.x) * ESC) * e1;
        const float dr = t0 - xjp;
        w += jr ? exp2f((Rr0 - dr * dr - Rc.x) * ESC) * Er0 : 0.0f;
        const float dd = t1 - xjp;
        w += jr ? exp2f((Rr1 - dd * dd - Rc.x) * ESC) * Er1 : 0.0f;
        e0 = w;
      }
      // temporal accumulation: i_k = 4p+k+1, Omega = (i-j)^2
      const float f0 = (float)(4 * p + 1 - j);
      const float f1 = f0 + 1.0f, f2 = f0 + 2.0f, f3 = f0 + 3.0f;
      tsum += (double)(e0 * f0 * f0) + (double)(e1 * f1 * f1) +
              (double)(e2 * f2 * f2) + (double)(e3 * f3 * f3);
      Rr0 = Rc.x; Rr1 = Rc.y; Rr2 = Rc.z; Rr3 = Rc.w;
      Er0 = e0; Er1 = e1; Er2 = e2; Er3 = e3;
    }
    // shuffles must be executed by ALL lanes (no divergence)
    const float srcR = act ? Rc.x : 0.0f;
    const float srcE = act ? e0 : 0.0f;
    bR1 = bR0; bE1 = bE0;
    bR0 = __shfl_down(srcR, 1);
    bE0 = __shfl_down(srcE, 1);
    Rc = Rnext;
  }

  // ---------------- wave reductions ----------------
  for (int off = 32; off > 0; off >>= 1) {
    tsum += __shfl_xor(tsum, off);
    msel += __shfl_xor(msel, off);
  }
  if (p == 0) {
    partial[b * 3 + 0] = (double)r_nn;
    partial[b * 3 + 1] = tsum;
    partial[b * 3 + 2] = msel;
  }
}

__global__ __launch_bounds__(64) void finalize_kernel(const double* __restrict__ partial,
                                                      float* __restrict__ out) {
  const int t = threadIdx.x;  // one lane per batch
  double sd = partial[t * 3 + 0];
  double ts = partial[t * 3 + 1];
  double ms = partial[t * 3 + 2];
  for (int off = 32; off > 0; off >>= 1) {
    sd += __shfl_xor(sd, off);
    ts += __shfl_xor(ts, off);
    ms += __shfl_xor(ms, off);
  }
  if (t == 0) {
    const double loss_shape = sd / (double)BB;
    const double loss_temporal = ts / ((double)BB * NN * NN);
    const double mse = ms / ((double)BB * NN);
    out[0] = (float)(0.5 * loss_shape + 0.5 * loss_temporal + mse);
  }
}

extern "C" void kernel_launch(void* const* d_in, const int* in_sizes, int n_in,
                              void* d_out, int out_size, void* d_ws, size_t ws_size,
                              hipStream_t stream) {
  const float* input = (const float*)d_in[0];
  const float* target = (const float*)d_in[1];
  float4* Rws = (float4*)d_ws;
  double* partial = (double*)((char*)d_ws + (size_t)BB * NSLAB * PP * sizeof(float4));
  float* out = (float*)d_out;

  sdtw_kernel<<<BB, PP, 0, stream>>>(input, target, Rws, partial);
  finalize_kernel<<<1, 64, 0, stream>>>(partial, out);
}